// Round 8
// baseline (435.534 us; speedup 1.0000x reference)
//
#include <hip/hip_runtime.h>
#include <stdint.h>

// LConv2d on MI355X (gfx950)
// B=8, CIN=COUT=128, L=128. out = center@f + sum_mu fw@T_fwd(f) + bw@T_bwd(f)
// Strategy: fused stencil-GEMM, MFMA 32x32x16 bf16, 3-product split (Wh,Wl)x(Bh,Bl)
// for ~fp32 accuracy. Link scalars folded into the B-fragment build (per-pixel
// column scaling), so all 5 directions accumulate into one f32 acc pair.
// Block = one (b, x) row: 128 pixels x 128 COUT, 512 threads = 8 waves (2M x 4N).
//
// R7: resubmission (infra failures R5-R7; the R4 fix has never executed).
// R4 FIX: W double-buffer base was (m&1)*2*WBUF_HALF halfwords — byte-size
// confused with halfword index -> odd iterations hit LDS beyond the 139264-B
// allocation (garbage W fragments, absmax err 20.4). Correct stride is
// WBUF_HALF (10240 halfwords = one [spl2][o128][k40] buffer).

#define LL    128
#define NCIN  128
#define NCOUT 128
#define NB    8

typedef __attribute__((ext_vector_type(8)))  __bf16 bf16x8;
typedef __attribute__((ext_vector_type(16))) float  f32x16;
typedef __attribute__((ext_vector_type(4)))  float  f32x4;

#define FEAT_BYTES 98304        // f32 [comp2][row3][i32][y128]
#define WBUF_HALF  10240        // halfwords per W buffer: [spl2][o128][k40pad]
#define LDS_BYTES  (FEAT_BYTES + 2 * 2 * 10240)   // 98304 + 40960 = 139264

__global__ __launch_bounds__(512, 2)
void lconv_kernel(const float* __restrict__ frg, const float* __restrict__ fig,
                  const float* __restrict__ links, const float* __restrict__ wc,
                  const float* __restrict__ wf, const float* __restrict__ wb,
                  float* __restrict__ out)
{
    extern __shared__ char smem[];
    float*  feat = (float*)smem;                 // [2][3][32][128] f32
    __bf16* wlds = (__bf16*)(smem + FEAT_BYTES); // [buf2][spl2][o128][k40]

    const int tid  = threadIdx.x;
    const int lane = tid & 63;
    const int wv   = tid >> 6;
    const int l5   = lane >> 5;   // 0,1
    const int ln   = lane & 31;   // 0..31
    const int Mrow = wv >> 2;     // 0,1  (o-range 64*Mrow)
    const int Ncol = wv & 3;      // 0..3 (pixel range 32*Ncol)

    // XCD-chunked swizzle: each XCD owns one batch b; consecutive dispatches on
    // an XCD are x-adjacent (share 2/3 of staged rows -> L2 reuse).
    const int bid     = blockIdx.x;
    const int logical = (bid & 7) * 128 + (bid >> 3);   // 1024 blocks, bijective
    const int b = logical >> 7;
    const int x = logical & 127;
    const int xm = (x + 127) & 127;

    const int y  = Ncol * 32 + ln;     // this lane's output pixel (B-frag col)
    const int yp = (y + 1) & 127;
    const int ym = (y + 127) & 127;

    // link scalars per direction (fixed per lane for whole kernel)
    // d=1 fwd-x: U_x(x,y); d=2 bwd-x: conj U_x(x-1,y); d=3 fwd-y: U_y(x,y);
    // d=4 bwd-y: conj U_y(x,y-1)
    const float* Lb = links + (size_t)b * 4 * LL * LL;
    const float lr1 =  Lb[(0*LL + x )*LL + y ];
    const float li1 =  Lb[(1*LL + x )*LL + y ];
    const float lr2 =  Lb[(0*LL + xm)*LL + y ];
    const float li2 = -Lb[(1*LL + xm)*LL + y ];
    const float lr3 =  Lb[(2*LL + x )*LL + y ];
    const float li3 =  Lb[(3*LL + x )*LL + y ];
    const float lr4 =  Lb[(2*LL + x )*LL + ym];
    const float li4 = -Lb[(3*LL + x )*LL + ym];

    f32x16 accR0 = {}, accR1 = {}, accI0 = {}, accI1 = {};

    // W staging assignment: thread -> (o row, k-octet)
    const int w_o  = tid >> 2;          // 0..127
    const int w_k0 = (tid & 3) * 8;     // 0,8,16,24

    // prologue: prefetch W chunk for m=0 (center, kc=0)
    f32x4 wr0, wr1;
    {
        const float* wp = wc + w_o * NCIN + w_k0;
        wr0 = *(const f32x4*)wp;
        wr1 = *(const f32x4*)(wp + 4);
    }

    for (int m = 0; m < 20; ++m) {
        const int kc  = m / 5;   // K-chunk (32 channels)
        const int d   = m % 5;   // 0=center 1=fwd-x 2=bwd-x 3=fwd-y 4=bwd-y
        const int wbb = (m & 1) * WBUF_HALF;   // halfword base of W buffer (R4 fix)

        // ---- write W(m) (prefetched regs) as bf16 hi/lo planes into buffer m&1.
        // The implicit vmcnt wait for the prefetch lands HERE, after a full
        // MFMA phase — hidden. Reads of this buffer (iter m-2) are separated
        // from this write by the iter m-1 barrier.
        {
            float w8[8] = { wr0.x, wr0.y, wr0.z, wr0.w, wr1.x, wr1.y, wr1.z, wr1.w };
            bf16x8 H, LO;
            #pragma unroll
            for (int e = 0; e < 8; ++e) {
                __bf16 h = (__bf16)w8[e];
                H[e]  = h;
                LO[e] = (__bf16)(w8[e] - (float)h);
            }
            *(bf16x8*)&wlds[wbb + w_o * 40 + w_k0]        = H;
            *(bf16x8*)&wlds[wbb + 5120 + w_o * 40 + w_k0] = LO;
        }

        if (d == 0) {
            __syncthreads();    // feat readers of previous kc done
            // stage features: rows x-1,x,x+1, channels kc*32..+32, both comps.
            // reg-staged float4 along y (coalesced 512B per 32 lanes).
            #pragma unroll
            for (int j = 0; j < 12; ++j) {
                const int q    = tid + j * 512;    // float4 slot 0..6143
                const int idx  = q * 4;            // f32 index into feat
                const int irow = idx >> 7;         // 0..191 = comp*96 + row*32 + i
                const int y0   = idx & 127;
                const int comp = (irow >= 96) ? 1 : 0;
                const int rr   = irow - comp * 96;
                const int row  = rr >> 5;          // 0..2  (x-1, x, x+1)
                const int io   = rr & 31;
                const int xs   = (x + row + 127) & 127;
                const float* g = (comp ? fig : frg)
                    + (((size_t)b * NCIN + (size_t)(kc * 32 + io)) * LL + xs) * LL + y0;
                *(f32x4*)(feat + idx) = *(const f32x4*)g;
            }
        }

        __syncthreads();        // W(m) plane + feat visible to all

        // ---- prefetch W(m+1) AFTER the barrier: loads fly across the MFMA
        // phase (nothing drains vmcnt until the ds_write at the top of m+1,
        // which lands after a full compute phase).
        if (m < 19) {
            const int m2 = m + 1;
            const int kc2 = m2 / 5, d2 = m2 % 5;
            const float* ws = (d2 == 0) ? wc
                            : (d2 == 1) ? wf
                            : (d2 == 2) ? wb
                            : (d2 == 3) ? (wf + NCOUT * NCIN)
                                        : (wb + NCOUT * NCIN);
            const float* wp = ws + w_o * NCIN + kc2 * 32 + w_k0;
            wr0 = *(const f32x4*)wp;
            wr1 = *(const f32x4*)(wp + 4);
        }

        // ---- compute phase
        const int   row_d = (d == 1) ? 2 : (d == 2) ? 0 : 1;
        const int   ysrc  = (d == 3) ? yp : (d == 4) ? ym : y;
        const float lr    = (d == 1) ? lr1 : (d == 2) ? lr2 : (d == 3) ? lr3
                          : (d == 4) ? lr4 : 1.0f;
        const float li    = (d == 1) ? li1 : (d == 2) ? li2 : (d == 3) ? li3
                          : (d == 4) ? li4 : 0.0f;

        const int fbr = row_d * 4096 + ysrc;            // comp 0 plane (f32 idx)
        const int fbi = 12288 + row_d * 4096 + ysrc;    // comp 1 plane

        #pragma unroll
        for (int kk = 0; kk < 2; ++kk) {                // two K=16 steps per chunk
            const int ib = kk * 16 + 8 * l5;            // lane's k-octet base
            float fr8[8], fi8[8];
            #pragma unroll
            for (int j = 0; j < 8; ++j) fr8[j] = feat[fbr + (ib + j) * 128];
            #pragma unroll
            for (int j = 0; j < 8; ++j) fi8[j] = feat[fbi + (ib + j) * 128];

            // build link-scaled B columns in f32, split to bf16 hi/lo
            bf16x8 Brh, Brl, Bih, Bil;
            #pragma unroll
            for (int j = 0; j < 8; ++j) {
                float br, bi2;
                if (d == 0) { br = fr8[j]; bi2 = fi8[j]; }
                else        { br  = lr * fr8[j] - li * fi8[j];
                              bi2 = lr * fi8[j] + li * fr8[j]; }
                __bf16 h1 = (__bf16)br;
                Brh[j] = h1; Brl[j] = (__bf16)(br - (float)h1);
                __bf16 h2 = (__bf16)bi2;
                Bih[j] = h2; Bil[j] = (__bf16)(bi2 - (float)h2);
            }

            #pragma unroll
            for (int mt = 0; mt < 2; ++mt) {
                const int oo = wbb + (Mrow * 64 + mt * 32 + ln) * 40 + kk * 16 + 8 * l5;
                bf16x8 Ah = *(bf16x8*)&wlds[oo];
                bf16x8 Al = *(bf16x8*)&wlds[5120 + oo];
                f32x16& aR = mt ? accR1 : accR0;
                f32x16& aI = mt ? accI1 : accI0;
                // 3-product split: Wh*Bh + Wh*Bl + Wl*Bh  (drop Wl*Bl, ~2^-18)
                aR = __builtin_amdgcn_mfma_f32_32x32x16_bf16(Ah, Brh, aR, 0, 0, 0);
                aR = __builtin_amdgcn_mfma_f32_32x32x16_bf16(Ah, Brl, aR, 0, 0, 0);
                aR = __builtin_amdgcn_mfma_f32_32x32x16_bf16(Al, Brh, aR, 0, 0, 0);
                aI = __builtin_amdgcn_mfma_f32_32x32x16_bf16(Ah, Bih, aI, 0, 0, 0);
                aI = __builtin_amdgcn_mfma_f32_32x32x16_bf16(Ah, Bil, aI, 0, 0, 0);
                aI = __builtin_amdgcn_mfma_f32_32x32x16_bf16(Al, Bih, aI, 0, 0, 0);
            }
        }
    }

    // epilogue: C/D layout 32x32: col = lane&31 (=pixel y-local),
    // row = (r&3) + 8*(r>>2) + 4*(lane>>5)  [m74/m101 verified mapping]
    // Non-temporal stores: output is write-once, never re-read — keep it out
    // of L2 so the reused feature window stays resident.
    const size_t OFF = (size_t)NB * NCOUT * LL * LL;    // out_i offset
    #pragma unroll
    for (int mt = 0; mt < 2; ++mt) {
        const f32x16 aR = mt ? accR1 : accR0;
        const f32x16 aI = mt ? accI1 : accI0;
        const int ob = Mrow * 64 + mt * 32 + 4 * l5;
        #pragma unroll
        for (int r = 0; r < 16; ++r) {
            const int o = ob + (r & 3) + 8 * (r >> 2);
            const size_t idx = (((size_t)(b * NCOUT + o)) * LL + x) * LL + y;
            __builtin_nontemporal_store(aR[r], &out[idx]);
            __builtin_nontemporal_store(aI[r], &out[OFF + idx]);
        }
    }
}

extern "C" void kernel_launch(void* const* d_in, const int* in_sizes, int n_in,
                              void* d_out, int out_size, void* d_ws, size_t ws_size,
                              hipStream_t stream) {
    (void)in_sizes; (void)n_in; (void)out_size; (void)d_ws; (void)ws_size;
    const float* frg   = (const float*)d_in[0];
    const float* fig   = (const float*)d_in[1];
    const float* links = (const float*)d_in[2];
    const float* wc    = (const float*)d_in[3];
    const float* wf    = (const float*)d_in[4];
    const float* wb    = (const float*)d_in[5];
    float* out = (float*)d_out;

    // dynamic LDS > 64KB needs the attribute; host-side, graph-capture safe,
    // idempotent (runs every call per harness rules)
    hipFuncSetAttribute((const void*)lconv_kernel,
                        hipFuncAttributeMaxDynamicSharedMemorySize, LDS_BYTES);

    lconv_kernel<<<dim3(1024), dim3(512), LDS_BYTES, stream>>>(
        frg, fig, links, wc, wf, wb, out);
}

// Round 9
// 311.309 us; speedup vs baseline: 1.3990x; 1.3990x over previous
//
#include <hip/hip_runtime.h>
#include <stdint.h>

// LConv2d on MI355X (gfx950)
// B=8, CIN=COUT=128, L=128. out = center@f + sum_mu fw@T_fwd(f) + bw@T_bwd(f)
// R9 (first counter-driven round; R8 PASSED at 296us/dispatch, MfmaUtil 18.7,
// VALUBusy 36.1, Occ 22.4, HBM 8.8% -> latency/barrier-bound + VALU-heavy):
//  1) 1-product bf16 (was 3-product split): MFMA/iter 24->8, B-build VALU ~-45%.
//     Error budget: bf16 1-product worst ~0.15 + 0.125 harness ref-floor << 0.6125.
//  2) W staged per-kc for ALL 5 directions (50KB LDS): the 5 direction phases
//     per K-chunk run BARRIER-FREE. Barriers/block 24 -> 7.
//  3) Compile-time weight-pointer selection in staging (no per-lane indexing).
// Block = one (b,x) row: 128 px x 128 COUT, 512 thr = 8 waves (2M x 4N).

#define LL    128
#define NCIN  128
#define NCOUT 128
#define NB    8

typedef __attribute__((ext_vector_type(8)))  __bf16 bf16x8;
typedef __attribute__((ext_vector_type(4)))  __bf16 bf16x4;
typedef __attribute__((ext_vector_type(16))) float  f32x16;
typedef __attribute__((ext_vector_type(4)))  float  f32x4;

#define FEAT_BYTES 98304            // f32 [comp2][row3][i32][y128]
#define WROW 40                     // halfwords per W row: 32 k + 8 pad (80B, 4-way-max banks)
#define W_BYTES (5 * 128 * WROW * 2)        // 51200
#define LDS_BYTES (FEAT_BYTES + W_BYTES)    // 149504 <= 160 KiB

__global__ __launch_bounds__(512, 2)
void lconv_kernel(const float* __restrict__ frg, const float* __restrict__ fig,
                  const float* __restrict__ links, const float* __restrict__ wc,
                  const float* __restrict__ wf, const float* __restrict__ wb,
                  float* __restrict__ out)
{
    extern __shared__ char smem[];
    float*  feat = (float*)smem;                 // [2][3][32][128] f32
    __bf16* wlds = (__bf16*)(smem + FEAT_BYTES); // [d5][o128][WROW] bf16

    const int tid  = threadIdx.x;
    const int lane = tid & 63;
    const int wv   = tid >> 6;
    const int l5   = lane >> 5;   // 0,1
    const int ln   = lane & 31;   // 0..31
    const int Mrow = wv >> 2;     // 0,1  (o-range 64*Mrow)
    const int Ncol = wv & 3;      // 0..3 (pixel range 32*Ncol)

    // XCD-chunked swizzle: each XCD owns one batch b; consecutive dispatches on
    // an XCD are x-adjacent (share 2/3 of staged rows -> L2 reuse).
    const int bid     = blockIdx.x;
    const int logical = (bid & 7) * 128 + (bid >> 3);   // 1024 blocks, bijective
    const int b = logical >> 7;
    const int x = logical & 127;
    const int xm = (x + 127) & 127;

    const int y  = Ncol * 32 + ln;     // this lane's output pixel (B-frag col)
    const int yp = (y + 1) & 127;
    const int ym = (y + 127) & 127;

    // link scalars per direction (fixed per lane for whole kernel)
    // d=1 fwd-x: U_x(x,y); d=2 bwd-x: conj U_x(x-1,y); d=3 fwd-y: U_y(x,y);
    // d=4 bwd-y: conj U_y(x,y-1)
    const float* Lb = links + (size_t)b * 4 * LL * LL;
    const float lr1 =  Lb[(0*LL + x )*LL + y ];
    const float li1 =  Lb[(1*LL + x )*LL + y ];
    const float lr2 =  Lb[(0*LL + xm)*LL + y ];
    const float li2 = -Lb[(1*LL + xm)*LL + y ];
    const float lr3 =  Lb[(2*LL + x )*LL + y ];
    const float li3 =  Lb[(3*LL + x )*LL + y ];
    const float lr4 =  Lb[(2*LL + x )*LL + ym];
    const float li4 = -Lb[(3*LL + x )*LL + ym];

    f32x16 accR0 = {}, accR1 = {}, accI0 = {}, accI1 = {};

    for (int kc = 0; kc < 4; ++kc) {
        if (kc > 0) __syncthreads();    // readers of previous kc done

        // ---- stage features: rows x-1,x,x+1, channels kc*32..+32, both comps.
        // reg-staged float4 along y (coalesced); 12 slots/thread.
        #pragma unroll
        for (int j = 0; j < 12; ++j) {
            const int q    = tid + j * 512;    // float4 slot 0..6143
            const int idx  = q * 4;            // f32 index into feat
            const int irow = idx >> 7;         // 0..191 = comp*96 + row*32 + i
            const int y0   = idx & 127;
            const int comp = (irow >= 96) ? 1 : 0;
            const int rr   = irow - comp * 96;
            const int row  = rr >> 5;          // 0..2  (x-1, x, x+1)
            const int io   = rr & 31;
            const int xs   = (x + row + 127) & 127;
            const float* g = (comp ? fig : frg)
                + (((size_t)b * NCIN + (size_t)(kc * 32 + io)) * LL + xs) * LL + y0;
            *(f32x4*)(feat + idx) = *(const f32x4*)g;
        }

        // ---- stage W for ALL 5 directions, this kc (bf16, 1-product).
        // slot s = j*512 + tid: d = j>>1 (compile-time per unrolled j),
        // r = (j&1)*512+tid, o = r>>3, k4 = (r&7)*4.
        #pragma unroll
        for (int j = 0; j < 10; ++j) {
            const int dd = j >> 1;
            const float* wsd = (dd == 0) ? wc
                             : (dd == 1) ? wf
                             : (dd == 2) ? wb
                             : (dd == 3) ? (wf + NCOUT * NCIN)
                                         : (wb + NCOUT * NCIN);
            const int r  = (j & 1) * 512 + tid;
            const int o  = r >> 3;
            const int k4 = (r & 7) * 4;
            const f32x4 w4 = *(const f32x4*)(wsd + o * NCIN + kc * 32 + k4);
            bf16x4 h;
            h[0] = (__bf16)w4.x; h[1] = (__bf16)w4.y;
            h[2] = (__bf16)w4.z; h[3] = (__bf16)w4.w;
            *(bf16x4*)&wlds[(dd * 128 + o) * WROW + k4] = h;
        }

        __syncthreads();        // feat + all-direction W visible

        // ---- 5 direction phases, NO barriers between them (all LDS read-only)
        #pragma unroll
        for (int d = 0; d < 5; ++d) {
            const int   row_d = (d == 1) ? 2 : (d == 2) ? 0 : 1;
            const int   ysrc  = (d == 3) ? yp : (d == 4) ? ym : y;
            const float lr    = (d == 1) ? lr1 : (d == 2) ? lr2 : (d == 3) ? lr3
                              : (d == 4) ? lr4 : 1.0f;
            const float li    = (d == 1) ? li1 : (d == 2) ? li2 : (d == 3) ? li3
                              : (d == 4) ? li4 : 0.0f;

            const int fbr = row_d * 4096 + ysrc;            // comp 0 plane (f32 idx)
            const int fbi = 12288 + row_d * 4096 + ysrc;    // comp 1 plane

            #pragma unroll
            for (int kk = 0; kk < 2; ++kk) {                // two K=16 steps
                const int ib = kk * 16 + 8 * l5;            // lane's k-octet base
                float fr8[8], fi8[8];
                #pragma unroll
                for (int j = 0; j < 8; ++j) fr8[j] = feat[fbr + (ib + j) * 128];
                #pragma unroll
                for (int j = 0; j < 8; ++j) fi8[j] = feat[fbi + (ib + j) * 128];

                // link-scaled B columns, single bf16 rounding (1-product)
                bf16x8 Br, Bi;
                #pragma unroll
                for (int j = 0; j < 8; ++j) {
                    float br, bi2;
                    if (d == 0) { br = fr8[j]; bi2 = fi8[j]; }
                    else        { br  = lr * fr8[j] - li * fi8[j];
                                  bi2 = lr * fi8[j] + li * fr8[j]; }
                    Br[j] = (__bf16)br;
                    Bi[j] = (__bf16)bi2;
                }

                #pragma unroll
                for (int mt = 0; mt < 2; ++mt) {
                    const int oo = (d * 128 + Mrow * 64 + mt * 32 + ln) * WROW
                                 + kk * 16 + 8 * l5;
                    const bf16x8 A = *(const bf16x8*)&wlds[oo];
                    f32x16& aR = mt ? accR1 : accR0;
                    f32x16& aI = mt ? accI1 : accI0;
                    aR = __builtin_amdgcn_mfma_f32_32x32x16_bf16(A, Br, aR, 0, 0, 0);
                    aI = __builtin_amdgcn_mfma_f32_32x32x16_bf16(A, Bi, aI, 0, 0, 0);
                }
            }
        }
    }

    // epilogue: C/D layout 32x32: col = lane&31 (=pixel y-local),
    // row = (r&3) + 8*(r>>2) + 4*(lane>>5)  [HW-validated by R8 pass]
    // Non-temporal stores: output is write-once dead data; preserve L2 for
    // the reused feature window.
    const size_t OFF = (size_t)NB * NCOUT * LL * LL;    // out_i offset
    #pragma unroll
    for (int mt = 0; mt < 2; ++mt) {
        const f32x16 aR = mt ? accR1 : accR0;
        const f32x16 aI = mt ? accI1 : accI0;
        const int ob = Mrow * 64 + mt * 32 + 4 * l5;
        #pragma unroll
        for (int r = 0; r < 16; ++r) {
            const int o = ob + (r & 3) + 8 * (r >> 2);
            const size_t idx = (((size_t)(b * NCOUT + o)) * LL + x) * LL + y;
            __builtin_nontemporal_store(aR[r], &out[idx]);
            __builtin_nontemporal_store(aI[r], &out[OFF + idx]);
        }
    }
}

extern "C" void kernel_launch(void* const* d_in, const int* in_sizes, int n_in,
                              void* d_out, int out_size, void* d_ws, size_t ws_size,
                              hipStream_t stream) {
    (void)in_sizes; (void)n_in; (void)out_size; (void)d_ws; (void)ws_size;
    const float* frg   = (const float*)d_in[0];
    const float* fig   = (const float*)d_in[1];
    const float* links = (const float*)d_in[2];
    const float* wc    = (const float*)d_in[3];
    const float* wf    = (const float*)d_in[4];
    const float* wb    = (const float*)d_in[5];
    float* out = (float*)d_out;

    // dynamic LDS > 64KB needs the attribute; host-side, graph-capture safe,
    // idempotent (runs every call per harness rules)
    hipFuncSetAttribute((const void*)lconv_kernel,
                        hipFuncAttributeMaxDynamicSharedMemorySize, LDS_BYTES);

    lconv_kernel<<<dim3(1024), dim3(512), LDS_BYTES, stream>>>(
        frg, fig, links, wc, wf, wb, out);
}

// Round 11
// 305.652 us; speedup vs baseline: 1.4249x; 1.0185x over previous
//
#include <hip/hip_runtime.h>
#include <stdint.h>

// LConv2d on MI355X (gfx950)
// B=8, CIN=COUT=128, L=128. out = center@f + sum_mu fw@T_fwd(f) + bw@T_bwd(f)
// R11 = R10 resubmitted (GPU unavailable; desk re-audit clean).
// R10 (R9: 158us PASS, MfmaUtil 10.9, VALUBusy 18, HBM 17.5 — LDS-pipe bound:
// 2560 scalar ds_read_b32/kc/CU ~= 62% of cycles):
//  1) feat in LDS as bf16 (fr,fi) PAIRS (one u32 per channel-pixel): half the
//     bytes, both comps per read.
//  2) Blocked-transposed layout [row][y/4][i32][y%4], block stride 132 dwords:
//     staging writes are contiguous ds_write_b128 (4-way-balanced = floor);
//     compute reads 8 stride-4 dwords -> ds_read2_b32 pairs, bank-BIJECTIVE
//     over 32 lanes (conflict-free), lanes l/l+32 2-way (free).
//  3) d==0 B-build via bit-extract (pairs already hold bf16 bits).
// Block = one (b,x) row: 128 px x 128 COUT, 512 thr = 8 waves (2M x 4N).

#define LL    128
#define NCIN  128
#define NCOUT 128
#define NB    8

typedef __attribute__((ext_vector_type(8)))  __bf16 bf16x8;
typedef __attribute__((ext_vector_type(4)))  __bf16 bf16x4;
typedef __attribute__((ext_vector_type(16))) float  f32x16;
typedef __attribute__((ext_vector_type(4)))  float  f32x4;
typedef __attribute__((ext_vector_type(4)))  uint32_t u32x4;

// feat pairs: [row3][yb32][i32][v4] u32; block pad 4 dwords
#define FP_BLOCK 132                    // dwords per (row,yb) block (128 + 4 pad)
#define FP_ROW   (32 * FP_BLOCK)        // 4224 dwords per row-plane
#define FP_DW    (3 * FP_ROW)           // 12672 dwords = 50688 B
#define WROW     40                     // halfwords per W row (32 k + 8 pad)
#define W_BYTES  (5 * 128 * WROW * 2)   // 51200 B
#define LDS_BYTES (FP_DW * 4 + W_BYTES) // 101888 B <= 160 KiB

__device__ __forceinline__ float pair_lo_f32(uint32_t p) {   // fr
    uint32_t v = p << 16; return __builtin_bit_cast(float, v);
}
__device__ __forceinline__ float pair_hi_f32(uint32_t p) {   // fi
    uint32_t v = p & 0xFFFF0000u; return __builtin_bit_cast(float, v);
}

__global__ __launch_bounds__(512, 2)
void lconv_kernel(const float* __restrict__ frg, const float* __restrict__ fig,
                  const float* __restrict__ links, const float* __restrict__ wc,
                  const float* __restrict__ wf, const float* __restrict__ wb,
                  float* __restrict__ out)
{
    extern __shared__ char smem[];
    uint32_t* fp   = (uint32_t*)smem;                 // feat pair store
    __bf16*   wlds = (__bf16*)(smem + FP_DW * 4);     // [d5][o128][WROW]

    const int tid  = threadIdx.x;
    const int lane = tid & 63;
    const int wv   = tid >> 6;
    const int l5   = lane >> 5;   // 0,1 (k-octet select)
    const int ln   = lane & 31;   // 0..31
    const int Mrow = wv >> 2;     // 0,1  (o-range 64*Mrow)
    const int Ncol = wv & 3;      // 0..3 (pixel range 32*Ncol)

    // XCD-chunked swizzle: each XCD owns one batch b; x-adjacent blocks share
    // 2/3 of staged rows -> L2 reuse.
    const int bid     = blockIdx.x;
    const int logical = (bid & 7) * 128 + (bid >> 3);   // bijective
    const int b = logical >> 7;
    const int x = logical & 127;
    const int xm = (x + 127) & 127;

    const int y  = Ncol * 32 + ln;     // lane's output pixel (B-frag col)
    const int yp = (y + 1) & 127;
    const int ym = (y + 127) & 127;

    // link scalars (d=1 fwd-x: U_x(x,y); d=2 bwd-x: conj U_x(x-1,y);
    //               d=3 fwd-y: U_y(x,y); d=4 bwd-y: conj U_y(x,y-1))
    const float* Lb = links + (size_t)b * 4 * LL * LL;
    const float lr1 =  Lb[(0*LL + x )*LL + y ];
    const float li1 =  Lb[(1*LL + x )*LL + y ];
    const float lr2 =  Lb[(0*LL + xm)*LL + y ];
    const float li2 = -Lb[(1*LL + xm)*LL + y ];
    const float lr3 =  Lb[(2*LL + x )*LL + y ];
    const float li3 =  Lb[(3*LL + x )*LL + y ];
    const float lr4 =  Lb[(2*LL + x )*LL + ym];
    const float li4 = -Lb[(3*LL + x )*LL + ym];

    f32x16 accR0 = {}, accR1 = {}, accI0 = {}, accI1 = {};

    for (int kc = 0; kc < 4; ++kc) {
        if (kc > 0) __syncthreads();    // readers of previous kc done

        // ---- stage features as bf16 pairs, blocked-transposed.
        // granule g = (row, io, yb): load frg/fig f32x4 along y (coalesced),
        // pack 4 pairs, ONE ds_write_b128 at [row][yb][io][0..3].
        #pragma unroll
        for (int j = 0; j < 6; ++j) {
            const int g   = tid + j * 512;     // 0..3071
            const int row = g >> 10;           // 0..2  (x-1, x, x+1)
            const int rem = g & 1023;
            const int io  = rem >> 5;          // 0..31 channel in chunk
            const int yb  = rem & 31;          // y-block
            const int xs  = (x + row + 127) & 127;
            const size_t ga = (((size_t)(b * NCIN + kc * 32 + io)) * LL + xs) * LL
                            + (size_t)(yb * 4);
            const f32x4 fr4 = *(const f32x4*)(frg + ga);
            const f32x4 fi4 = *(const f32x4*)(fig + ga);
            u32x4 pk;
            #pragma unroll
            for (int v = 0; v < 4; ++v) {
                const uint32_t lo = (uint32_t)__builtin_bit_cast(uint16_t, (__bf16)fr4[v]);
                const uint32_t hi = (uint32_t)__builtin_bit_cast(uint16_t, (__bf16)fi4[v]);
                pk[v] = (hi << 16) | lo;
            }
            *(u32x4*)(fp + row * FP_ROW + yb * FP_BLOCK + io * 4) = pk;
        }

        // ---- stage W (bf16) for ALL 5 directions, this kc.
        #pragma unroll
        for (int j = 0; j < 10; ++j) {
            const int dd = j >> 1;             // compile-time per unrolled j
            const float* wsd = (dd == 0) ? wc
                             : (dd == 1) ? wf
                             : (dd == 2) ? wb
                             : (dd == 3) ? (wf + NCOUT * NCIN)
                                         : (wb + NCOUT * NCIN);
            const int r  = (j & 1) * 512 + tid;
            const int o  = r >> 3;
            const int k4 = (r & 7) * 4;
            const f32x4 w4 = *(const f32x4*)(wsd + o * NCIN + kc * 32 + k4);
            bf16x4 h;
            h[0] = (__bf16)w4.x; h[1] = (__bf16)w4.y;
            h[2] = (__bf16)w4.z; h[3] = (__bf16)w4.w;
            *(bf16x4*)&wlds[(dd * 128 + o) * WROW + k4] = h;
        }

        __syncthreads();        // feat + all-direction W visible

        // ---- 5 direction phases, barrier-free (all LDS read-only)
        #pragma unroll
        for (int d = 0; d < 5; ++d) {
            const int   row_d = (d == 1) ? 2 : (d == 2) ? 0 : 1;
            const int   ysrc  = (d == 3) ? yp : (d == 4) ? ym : y;
            const float lr    = (d == 1) ? lr1 : (d == 2) ? lr2 : (d == 3) ? lr3
                              : (d == 4) ? lr4 : 1.0f;
            const float li    = (d == 1) ? li1 : (d == 2) ? li2 : (d == 3) ? li3
                              : (d == 4) ? li4 : 0.0f;

            // lane's base: [row_d][ysrc>>2][i][ysrc&3]
            const int base = row_d * FP_ROW + (ysrc >> 2) * FP_BLOCK + (ysrc & 3);

            #pragma unroll
            for (int kk = 0; kk < 2; ++kk) {                // two K=16 steps
                const int ib = kk * 16 + 8 * l5;            // lane's k-octet
                uint32_t p[8];
                #pragma unroll
                for (int j = 0; j < 8; ++j)
                    p[j] = fp[base + (ib + j) * 4];         // -> ds_read2_b32

                bf16x8 Br, Bi;
                if (d == 0) {
                    // pairs already hold rounded bf16 bits: pure bit-extract
                    u32x4 br, bi;
                    #pragma unroll
                    for (int q = 0; q < 4; ++q) {
                        br[q] = (p[2*q] & 0xFFFFu) | (p[2*q+1] << 16);
                        bi[q] = (p[2*q] >> 16)     | (p[2*q+1] & 0xFFFF0000u);
                    }
                    Br = __builtin_bit_cast(bf16x8, br);
                    Bi = __builtin_bit_cast(bf16x8, bi);
                } else {
                    #pragma unroll
                    for (int j = 0; j < 8; ++j) {
                        const float fr = pair_lo_f32(p[j]);
                        const float fi = pair_hi_f32(p[j]);
                        Br[j] = (__bf16)(lr * fr - li * fi);
                        Bi[j] = (__bf16)(lr * fi + li * fr);
                    }
                }

                #pragma unroll
                for (int mt = 0; mt < 2; ++mt) {
                    const int oo = (d * 128 + Mrow * 64 + mt * 32 + ln) * WROW
                                 + kk * 16 + 8 * l5;
                    const bf16x8 A = *(const bf16x8*)&wlds[oo];
                    f32x16& aR = mt ? accR1 : accR0;
                    f32x16& aI = mt ? accI1 : accI0;
                    aR = __builtin_amdgcn_mfma_f32_32x32x16_bf16(A, Br, aR, 0, 0, 0);
                    aI = __builtin_amdgcn_mfma_f32_32x32x16_bf16(A, Bi, aI, 0, 0, 0);
                }
            }
        }
    }

    // epilogue: C/D 32x32: col = lane&31 (=pixel y), row = (r&3)+8*(r>>2)+4*l5
    // [HW-validated by R8/R9 pass]. NT stores keep dead output out of L2.
    const size_t OFF = (size_t)NB * NCOUT * LL * LL;
    #pragma unroll
    for (int mt = 0; mt < 2; ++mt) {
        const f32x16 aR = mt ? accR1 : accR0;
        const f32x16 aI = mt ? accI1 : accI0;
        const int ob = Mrow * 64 + mt * 32 + 4 * l5;
        #pragma unroll
        for (int r = 0; r < 16; ++r) {
            const int o = ob + (r & 3) + 8 * (r >> 2);
            const size_t idx = (((size_t)(b * NCOUT + o)) * LL + x) * LL + y;
            __builtin_nontemporal_store(aR[r], &out[idx]);
            __builtin_nontemporal_store(aI[r], &out[OFF + idx]);
        }
    }
}

extern "C" void kernel_launch(void* const* d_in, const int* in_sizes, int n_in,
                              void* d_out, int out_size, void* d_ws, size_t ws_size,
                              hipStream_t stream) {
    (void)in_sizes; (void)n_in; (void)out_size; (void)d_ws; (void)ws_size;
    const float* frg   = (const float*)d_in[0];
    const float* fig   = (const float*)d_in[1];
    const float* links = (const float*)d_in[2];
    const float* wc    = (const float*)d_in[3];
    const float* wf    = (const float*)d_in[4];
    const float* wb    = (const float*)d_in[5];
    float* out = (float*)d_out;

    // dynamic LDS > 64KB needs the attribute; host-side, graph-capture safe,
    // idempotent (runs every call per harness rules)
    hipFuncSetAttribute((const void*)lconv_kernel,
                        hipFuncAttributeMaxDynamicSharedMemorySize, LDS_BYTES);

    lconv_kernel<<<dim3(1024), dim3(512), LDS_BYTES, stream>>>(
        frg, fig, links, wc, wf, wb, out);
}

// Round 12
// 295.021 us; speedup vs baseline: 1.4763x; 1.0360x over previous
//
#include <hip/hip_runtime.h>
#include <stdint.h>

// LConv2d on MI355X (gfx950)
// B=8, CIN=COUT=128, L=128. out = center@f + sum_mu fw@T_fwd(f) + bw@T_bwd(f)
// R12 (R11: 157us — IDENTICAL to R9 despite halved feat-LDS work -> NOT
// LDS-throughput-bound. Decoded SQ_LDS_BANK_CONFLICT 1.31M = exactly 2cyc x
// 655360 W-b128 reads (stride 80B, 4-way); feat reads clean. Pipes all <25%,
// ~70% stall: LATENCY-bound at 1 block/CU = 2 waves/SIMD.)
// Fix: OCCUPANCY. 16-channel K-chunks (8 kc iters): feat 26.1KB + W 25.6KB =
// 51.7KB LDS -> 2 blocks/CU = 4 waves/SIMD (2x TLP, cross-block overlap of
// stage/barrier). W reads now 2x ds_read_b64 @ 40B stride (2-way = free) ->
// bank conflicts ~0. launch_bounds(512,4) pins VGPR<=128 (measured 88).
// Block = one (b,x) row: 128 px x 128 COUT, 512 thr = 8 waves (2M x 4N).

#define LL    128
#define NCIN  128
#define NCOUT 128
#define NB    8

typedef __attribute__((ext_vector_type(8)))  __bf16 bf16x8;
typedef __attribute__((ext_vector_type(4)))  __bf16 bf16x4;
typedef __attribute__((ext_vector_type(16))) float  f32x16;
typedef __attribute__((ext_vector_type(4)))  float  f32x4;
typedef __attribute__((ext_vector_type(4)))  uint32_t u32x4;

// feat pairs: [row3][yb32][i16][v4] u32; block pad 4 dwords
#define FPB   68                        // dwords per (row,yb) block (64 + 4 pad)
#define FPROW (32 * FPB)                // 2176 dwords per row-plane
#define FPDW  (3 * FPROW)               // 6528 dwords = 26112 B
#define WROW  20                        // halfwords per W row (16 k + 4 pad = 40B)
#define W_BYTES (5 * 128 * WROW * 2)    // 25600 B
#define LDS_BYTES (FPDW * 4 + W_BYTES)  // 51712 B -> 2 blocks/CU

__device__ __forceinline__ float pair_lo_f32(uint32_t p) {   // fr
    uint32_t v = p << 16; return __builtin_bit_cast(float, v);
}
__device__ __forceinline__ float pair_hi_f32(uint32_t p) {   // fi
    uint32_t v = p & 0xFFFF0000u; return __builtin_bit_cast(float, v);
}

__global__ __launch_bounds__(512, 4)
void lconv_kernel(const float* __restrict__ frg, const float* __restrict__ fig,
                  const float* __restrict__ links, const float* __restrict__ wc,
                  const float* __restrict__ wf, const float* __restrict__ wb,
                  float* __restrict__ out)
{
    extern __shared__ char smem[];
    uint32_t* fp   = (uint32_t*)smem;                 // feat pair store
    __bf16*   wlds = (__bf16*)(smem + FPDW * 4);      // [d5][o128][WROW]

    const int tid  = threadIdx.x;
    const int lane = tid & 63;
    const int wv   = tid >> 6;
    const int l5   = lane >> 5;   // 0,1 (k-octet select)
    const int ln   = lane & 31;   // 0..31
    const int Mrow = wv >> 2;     // 0,1  (o-range 64*Mrow)
    const int Ncol = wv & 3;      // 0..3 (pixel range 32*Ncol)

    // XCD-chunked swizzle: each XCD owns one batch b; x-adjacent blocks share
    // 2/3 of staged rows -> L2 reuse.
    const int bid     = blockIdx.x;
    const int logical = (bid & 7) * 128 + (bid >> 3);   // bijective
    const int b = logical >> 7;
    const int x = logical & 127;
    const int xm = (x + 127) & 127;

    const int y  = Ncol * 32 + ln;     // lane's output pixel (B-frag col)
    const int yp = (y + 1) & 127;
    const int ym = (y + 127) & 127;

    // link scalars (d=1 fwd-x: U_x(x,y); d=2 bwd-x: conj U_x(x-1,y);
    //               d=3 fwd-y: U_y(x,y); d=4 bwd-y: conj U_y(x,y-1))
    const float* Lb = links + (size_t)b * 4 * LL * LL;
    const float lr1 =  Lb[(0*LL + x )*LL + y ];
    const float li1 =  Lb[(1*LL + x )*LL + y ];
    const float lr2 =  Lb[(0*LL + xm)*LL + y ];
    const float li2 = -Lb[(1*LL + xm)*LL + y ];
    const float lr3 =  Lb[(2*LL + x )*LL + y ];
    const float li3 =  Lb[(3*LL + x )*LL + y ];
    const float lr4 =  Lb[(2*LL + x )*LL + ym];
    const float li4 = -Lb[(3*LL + x )*LL + ym];

    f32x16 accR0 = {}, accR1 = {}, accI0 = {}, accI1 = {};

    for (int kc = 0; kc < 8; ++kc) {     // 16-channel chunks
        if (kc > 0) __syncthreads();     // readers of previous kc done

        // ---- stage features as bf16 pairs, blocked-transposed.
        // j = row (compile-time): io = tid>>5 (0..15), yb = tid&31.
        // f32x4 along y (coalesced) -> pack 4 pairs -> one ds_write_b128.
        #pragma unroll
        for (int j = 0; j < 3; ++j) {
            const int io = tid >> 5;
            const int yb = tid & 31;
            const int xs = (x + j + 127) & 127;        // rows x-1, x, x+1
            const size_t ga = (((size_t)(b * NCIN + kc * 16 + io)) * LL + xs) * LL
                            + (size_t)(yb * 4);
            const f32x4 fr4 = *(const f32x4*)(frg + ga);
            const f32x4 fi4 = *(const f32x4*)(fig + ga);
            u32x4 pk;
            #pragma unroll
            for (int v = 0; v < 4; ++v) {
                const uint32_t lo = (uint32_t)__builtin_bit_cast(uint16_t, (__bf16)fr4[v]);
                const uint32_t hi = (uint32_t)__builtin_bit_cast(uint16_t, (__bf16)fi4[v]);
                pk[v] = (hi << 16) | lo;
            }
            *(u32x4*)(fp + j * FPROW + yb * FPB + io * 4) = pk;
        }

        // ---- stage W (bf16) for ALL 5 directions, this kc. j = dir.
        #pragma unroll
        for (int j = 0; j < 5; ++j) {
            const float* wsd = (j == 0) ? wc
                             : (j == 1) ? wf
                             : (j == 2) ? wb
                             : (j == 3) ? (wf + NCOUT * NCIN)
                                        : (wb + NCOUT * NCIN);
            const int o  = tid >> 2;
            const int k4 = (tid & 3) * 4;
            const f32x4 w4 = *(const f32x4*)(wsd + o * NCIN + kc * 16 + k4);
            bf16x4 h;
            h[0] = (__bf16)w4.x; h[1] = (__bf16)w4.y;
            h[2] = (__bf16)w4.z; h[3] = (__bf16)w4.w;
            *(bf16x4*)&wlds[(j * 128 + o) * WROW + k4] = h;   // 8B-aligned b64
        }

        __syncthreads();        // feat + all-direction W visible

        // ---- 5 direction phases, barrier-free (all LDS read-only)
        #pragma unroll
        for (int d = 0; d < 5; ++d) {
            const int   row_d = (d == 1) ? 2 : (d == 2) ? 0 : 1;
            const int   ysrc  = (d == 3) ? yp : (d == 4) ? ym : y;
            const float lr    = (d == 1) ? lr1 : (d == 2) ? lr2 : (d == 3) ? lr3
                              : (d == 4) ? lr4 : 1.0f;
            const float li    = (d == 1) ? li1 : (d == 2) ? li2 : (d == 3) ? li3
                              : (d == 4) ? li4 : 0.0f;

            // lane's base: [row_d][ysrc>>2][i][ysrc&3]; i = 8*l5 + j
            const int base = row_d * FPROW + (ysrc >> 2) * FPB + (ysrc & 3);

            uint32_t p[8];
            #pragma unroll
            for (int j = 0; j < 8; ++j)
                p[j] = fp[base + (8 * l5 + j) * 4];     // -> ds_read2_b32 pairs

            bf16x8 Br, Bi;
            if (d == 0) {
                // pairs already hold rounded bf16 bits: pure bit-extract
                u32x4 br, bi;
                #pragma unroll
                for (int q = 0; q < 4; ++q) {
                    br[q] = (p[2*q] & 0xFFFFu) | (p[2*q+1] << 16);
                    bi[q] = (p[2*q] >> 16)     | (p[2*q+1] & 0xFFFF0000u);
                }
                Br = __builtin_bit_cast(bf16x8, br);
                Bi = __builtin_bit_cast(bf16x8, bi);
            } else {
                #pragma unroll
                for (int j = 0; j < 8; ++j) {
                    const float fr = pair_lo_f32(p[j]);
                    const float fi = pair_hi_f32(p[j]);
                    Br[j] = (__bf16)(lr * fr - li * fi);
                    Bi[j] = (__bf16)(lr * fi + li * fr);
                }
            }

            #pragma unroll
            for (int mt = 0; mt < 2; ++mt) {
                // A row o = d-plane row; k-octet at 8*l5 (16B at 40B row
                // stride -> read as two 8B b64s: 2-way bank alias = free)
                const int ro = (d * 128 + Mrow * 64 + mt * 32 + ln) * WROW + 8 * l5;
                const bf16x4 a0 = *(const bf16x4*)&wlds[ro];
                const bf16x4 a1 = *(const bf16x4*)&wlds[ro + 4];
                bf16x8 A;
                #pragma unroll
                for (int e = 0; e < 4; ++e) { A[e] = a0[e]; A[4 + e] = a1[e]; }
                f32x16& aR = mt ? accR1 : accR0;
                f32x16& aI = mt ? accI1 : accI0;
                aR = __builtin_amdgcn_mfma_f32_32x32x16_bf16(A, Br, aR, 0, 0, 0);
                aI = __builtin_amdgcn_mfma_f32_32x32x16_bf16(A, Bi, aI, 0, 0, 0);
            }
        }
    }

    // epilogue: C/D 32x32: col = lane&31 (=pixel y), row = (r&3)+8*(r>>2)+4*l5
    // [HW-validated R8/R9/R11]. NT stores keep dead output out of L2.
    const size_t OFF = (size_t)NB * NCOUT * LL * LL;
    #pragma unroll
    for (int mt = 0; mt < 2; ++mt) {
        const f32x16 aR = mt ? accR1 : accR0;
        const f32x16 aI = mt ? accI1 : accI0;
        const int ob = Mrow * 64 + mt * 32 + 4 * l5;
        #pragma unroll
        for (int r = 0; r < 16; ++r) {
            const int o = ob + (r & 3) + 8 * (r >> 2);
            const size_t idx = (((size_t)(b * NCOUT + o)) * LL + x) * LL + y;
            __builtin_nontemporal_store(aR[r], &out[idx]);
            __builtin_nontemporal_store(aI[r], &out[OFF + idx]);
        }
    }
}

extern "C" void kernel_launch(void* const* d_in, const int* in_sizes, int n_in,
                              void* d_out, int out_size, void* d_ws, size_t ws_size,
                              hipStream_t stream) {
    (void)in_sizes; (void)n_in; (void)out_size; (void)d_ws; (void)ws_size;
    const float* frg   = (const float*)d_in[0];
    const float* fig   = (const float*)d_in[1];
    const float* links = (const float*)d_in[2];
    const float* wc    = (const float*)d_in[3];
    const float* wf    = (const float*)d_in[4];
    const float* wb    = (const float*)d_in[5];
    float* out = (float*)d_out;

    lconv_kernel<<<dim3(1024), dim3(512), LDS_BYTES, stream>>>(
        frg, fig, links, wc, wf, wb, out);
}